// Round 7
// baseline (193.038 us; speedup 1.0000x reference)
//
#include <hip/hip_runtime.h>
#include <hip/hip_bf16.h>

#define DIM 256
#define MEMN 512
#define TEMPF 10.0f

typedef float f32x4 __attribute__((ext_vector_type(4)));
typedef __bf16 bf16x8 __attribute__((ext_vector_type(8)));
typedef unsigned int u32;
typedef unsigned short u16;

__device__ __forceinline__ u16 bf16bits(float x) {
  __bf16 h = (__bf16)x;
  return __builtin_bit_cast(u16, h);
}
__device__ __forceinline__ u32 pack2(float a, float b) {
  return (u32)bf16bits(a) | ((u32)bf16bits(b) << 16);
}

// KnFrag[kc][mt][lane][j] = Kn_norm[mt*16+(lane&15)][kc*32+(lane>>4)*8+j], kc<8, mt<32
__global__ void prep_keys(const float* __restrict__ keys, u16* __restrict__ knf) {
  int lane = threadIdx.x & 63;
  int m = blockIdx.x * 4 + (threadIdx.x >> 6);
  float4 v = *reinterpret_cast<const float4*>(keys + (size_t)m * DIM + lane * 4);
  float ss = v.x*v.x + v.y*v.y + v.z*v.z + v.w*v.w;
  #pragma unroll
  for (int o = 1; o < 64; o <<= 1) ss += __shfl_xor(ss, o);
  float rn = 1.0f / fmaxf(sqrtf(ss), 1e-12f);
  float vals[4] = {v.x*rn, v.y*rn, v.z*rn, v.w*rn};
  int mt = m >> 4, ml = m & 15;
  #pragma unroll
  for (int t = 0; t < 4; ++t) {
    int d = lane * 4 + t;
    int kc = d >> 5, gg = (d >> 3) & 3, j = d & 7;
    knf[(size_t)((kc*32 + mt)*64 + gg*16 + ml)*8 + j] = bf16bits(vals[t]);
  }
}

// VtFrag[kc][dt][lane][j] = V[kc*32+(lane>>4)*8+j][dt*16+(lane&15)], kc<16, dt<16
__global__ void prep_vals(const float* __restrict__ mv, u16* __restrict__ vtf) {
  int lane = threadIdx.x & 63;
  int m = blockIdx.x * 4 + (threadIdx.x >> 6);
  float4 v = *reinterpret_cast<const float4*>(mv + (size_t)m * DIM + lane * 4);
  float vals[4] = {v.x, v.y, v.z, v.w};
  int kc = m >> 5, gg = (m >> 3) & 3, j = m & 7;
  #pragma unroll
  for (int t = 0; t < 4; ++t) {
    int d = lane * 4 + t;
    int dt = d >> 4, dl = d & 15;
    vtf[(size_t)((kc*16 + dt)*64 + gg*16 + dl)*8 + j] = bf16bits(vals[t]);
  }
}

// 256 threads (4 waves), 32 rows/block, 4 blocks/CU (LDS 33.8 KB, VGPR<=128).
// GEMM1: wave w owns m-quarter [128w,128w+128) x all 32 rows (Q B-frags via LDS).
// GEMM2: wave w owns d-quarter [64w,64w+64)   x all 32 rows (W B-frags via LDS).
// A-fragments (K,V) load directly from global (L2-resident; same addrs across
// blocks on a CU -> L1 reuse). 3 barriers; all LDS fragment-native (lane*16).
__global__ __launch_bounds__(256, 4) void fused_main(
    const float* __restrict__ q, const u16* __restrict__ knf,
    const u16* __restrict__ vtf, float* __restrict__ out_o,
    float* __restrict__ out_w, float* __restrict__ out_s) {
  // [0,16384): Q-frags (gr*8+kc)*1024 + lane*16 (dead after GEMM1)
  // [0,32768): W-frags (kc2*2+gr)*1024 + lane*16 (overlays Q after barrier #2)
  // [32768,33280): psb row-sum partials [(w*2+gr)*16+c]
  // [33280,33536): ssp ||q||^2 partials [(kh*2+gr)*16+c]
  // [33536,33792): sdp scene-diff partials
  __shared__ __align__(16) char lds[33792];
  const int tid = threadIdx.x;
  const int wave = tid >> 6, lane = tid & 63;
  const int g = lane >> 4, c = lane & 15;
  const int grw = wave & 1;        // row-group this wave loads in prologue
  const int kh  = wave >> 1;       // kc-half this wave loads in prologue
  const int browbase = blockIdx.x * 32;

  float* psb = reinterpret_cast<float*>(lds + 32768);
  float* ssp = reinterpret_cast<float*>(lds + 33280);
  float* sdp = reinterpret_cast<float*>(lds + 33536);

  // ---- prologue: wave loads rows grw*16+c, kc in [4kh,4kh+4) -> bf16 frags
  const int myrow = browbase + grw * 16 + c;
  const float* qrow = q + (size_t)myrow * DIM + g * 8;
  float sd = 0.f, ss = 0.f;
  #pragma unroll
  for (int j = 0; j < 4; ++j) {
    int kc = kh * 4 + j;
    float4 a = *reinterpret_cast<const float4*>(qrow + kc * 32);
    float4 b = *reinterpret_cast<const float4*>(qrow + kc * 32 + 4);
    float x[8] = {a.x, a.y, a.z, a.w, b.x, b.y, b.z, b.w};
    bf16x8 qb;
    #pragma unroll
    for (int e = 0; e < 8; ++e) {
      float nb = __shfl_down(x[e], 1);     // row c+1 same group (valid c<15)
      float d0 = nb - x[e];
      sd += d0 * d0;
      ss += x[e] * x[e];
      qb[e] = (__bf16)x[e];                // deferred norm -> exp scale
    }
    *reinterpret_cast<bf16x8*>(lds + (grw*8 + kc)*1024 + lane*16) = qb;
  }
  sd += __shfl_xor(sd, 16); sd += __shfl_xor(sd, 32);
  ss += __shfl_xor(ss, 16); ss += __shfl_xor(ss, 32);
  if (g == 0) {
    ssp[(kh*2 + grw)*16 + c] = ss;
    sdp[(kh*2 + grw)*16 + c] = sd;
  }
  __syncthreads();                          // #1: Q-frags + partials visible

  // scene out (rows with c<15 in each 16-group; c==15 via scene_bound kernel)
  if (kh == 0 && g == 0 && c < 15) {
    float sdt = sdp[grw*16 + c] + sdp[(2 + grw)*16 + c];
    out_s[myrow] = (sqrtf(sdt) < 0.8f) ? 1.0f : 0.0f;
  }
  float scale_r[2];
  #pragma unroll
  for (int gr = 0; gr < 2; ++gr) {
    float t = ssp[gr*16 + c] + ssp[(2 + gr)*16 + c];
    scale_r[gr] = TEMPF / fmaxf(sqrtf(t), 1e-12f);
  }

  // ---- GEMM1: S^T[m in wave-quarter][32 rows]; A (K) direct from L2
  f32x4 acc[8][2];
  #pragma unroll
  for (int mt = 0; mt < 8; ++mt)
    #pragma unroll
    for (int gr = 0; gr < 2; ++gr) { f32x4 z = {}; acc[mt][gr] = z; }

  #pragma unroll
  for (int kc = 0; kc < 8; ++kc) {
    bf16x8 bfr[2];
    #pragma unroll
    for (int gr = 0; gr < 2; ++gr)
      bfr[gr] = *reinterpret_cast<const bf16x8*>(lds + (gr*8 + kc)*1024 + lane*16);
    bf16x8 afr[8];
    #pragma unroll
    for (int mt = 0; mt < 8; ++mt)
      afr[mt] = *reinterpret_cast<const bf16x8*>(
          knf + (size_t)(kc*32 + wave*8 + mt)*512 + lane*8);
    #pragma unroll
    for (int mt = 0; mt < 8; ++mt)
      #pragma unroll
      for (int gr = 0; gr < 2; ++gr)
        acc[mt][gr] = __builtin_amdgcn_mfma_f32_16x16x32_bf16(afr[mt], bfr[gr], acc[mt][gr], 0, 0, 0);
  }
  // acc[mt][gr][i] = S^T[m=(8w+mt)*16+4g+i][row=gr*16+c]

  // ---- exp + partial row sums
  float psum[2] = {0.f, 0.f};
  #pragma unroll
  for (int mt = 0; mt < 8; ++mt)
    #pragma unroll
    for (int gr = 0; gr < 2; ++gr)
      #pragma unroll
      for (int i = 0; i < 4; ++i) {
        float e = __expf(acc[mt][gr][i] * scale_r[gr]);
        acc[mt][gr][i] = e;
        psum[gr] += e;
      }
  #pragma unroll
  for (int gr = 0; gr < 2; ++gr) {
    psum[gr] += __shfl_xor(psum[gr], 16);
    psum[gr] += __shfl_xor(psum[gr], 32);
  }
  if (g == 0) {
    #pragma unroll
    for (int gr = 0; gr < 2; ++gr)
      psb[(wave*2 + gr)*16 + c] = psum[gr];
  }
  __syncthreads();                          // #2: partials visible; GEMM1 reads done

  float rcp_r[2];
  #pragma unroll
  for (int gr = 0; gr < 2; ++gr) {
    float t = psb[(0*2 + gr)*16 + c] + psb[(1*2 + gr)*16 + c]
            + psb[(2*2 + gr)*16 + c] + psb[(3*2 + gr)*16 + c];
    rcp_r[gr] = 1.0f / t;
  }

  // ---- W-frags (bf16, rcp-folded) into LDS (overlays Q region)
  // slot (kc2,gr): lane (g2,c2) j holds W[gr*16+c2][kc2*32+g2*8+j]
  // writer: kc2=4w+(mt>>1), g2=(mt&1)*2+(g>>1), j0=(g&1)*4
  #pragma unroll
  for (int mt = 0; mt < 8; ++mt) {
    int kc2 = 4*wave + (mt >> 1);
    int lane_t = ((mt & 1)*2 + (g >> 1))*16 + c;
    #pragma unroll
    for (int gr = 0; gr < 2; ++gr) {
      u32 lo = pack2(acc[mt][gr][0]*rcp_r[gr], acc[mt][gr][1]*rcp_r[gr]);
      u32 hi = pack2(acc[mt][gr][2]*rcp_r[gr], acc[mt][gr][3]*rcp_r[gr]);
      u32* dst = reinterpret_cast<u32*>(lds + (size_t)(kc2*2 + gr)*1024 + lane_t*16 + (g & 1)*8);
      dst[0] = lo; dst[1] = hi;
    }
  }
  // W f32 global burst (acc dies here -> GEMM2 register pressure stays low)
  #pragma unroll
  for (int mt = 0; mt < 8; ++mt)
    #pragma unroll
    for (int gr = 0; gr < 2; ++gr) {
      float4 wv = { acc[mt][gr][0]*rcp_r[gr], acc[mt][gr][1]*rcp_r[gr],
                    acc[mt][gr][2]*rcp_r[gr], acc[mt][gr][3]*rcp_r[gr] };
      *reinterpret_cast<float4*>(out_w + (size_t)(browbase + gr*16 + c)*MEMN
                                 + (wave*8 + mt)*16 + 4*g) = wv;
    }
  __syncthreads();                          // #3: W-frags visible

  // ---- GEMM2: O^T[d in wave-quarter][32 rows]; A (V) direct from L2
  f32x4 oacc[4][2];
  #pragma unroll
  for (int dt = 0; dt < 4; ++dt)
    #pragma unroll
    for (int gr = 0; gr < 2; ++gr) { f32x4 z = {}; oacc[dt][gr] = z; }

  #pragma unroll
  for (int kc2 = 0; kc2 < 16; ++kc2) {
    bf16x8 bfr[2];
    #pragma unroll
    for (int gr = 0; gr < 2; ++gr)
      bfr[gr] = *reinterpret_cast<const bf16x8*>(lds + (size_t)(kc2*2 + gr)*1024 + lane*16);
    bf16x8 afr[4];
    #pragma unroll
    for (int dt = 0; dt < 4; ++dt)
      afr[dt] = *reinterpret_cast<const bf16x8*>(
          vtf + (size_t)(kc2*16 + wave*4 + dt)*512 + lane*8);
    #pragma unroll
    for (int dt = 0; dt < 4; ++dt)
      #pragma unroll
      for (int gr = 0; gr < 2; ++gr)
        oacc[dt][gr] = __builtin_amdgcn_mfma_f32_16x16x32_bf16(afr[dt], bfr[gr], oacc[dt][gr], 0, 0, 0);
  }

  // ---- O store (weights pre-normalized)
  #pragma unroll
  for (int dt = 0; dt < 4; ++dt)
    #pragma unroll
    for (int gr = 0; gr < 2; ++gr) {
      float4 ov = { oacc[dt][gr][0], oacc[dt][gr][1], oacc[dt][gr][2], oacc[dt][gr][3] };
      *reinterpret_cast<float4*>(out_o + (size_t)(browbase + gr*16 + c)*DIM
                                 + (wave*4 + dt)*16 + 4*g) = ov;
    }
}

// Boundary scene diffs: i % 16 == 15 (one wave per i)
__global__ void scene_bound(const float* __restrict__ q, float* __restrict__ out_s, int B) {
  int widx = (blockIdx.x * blockDim.x + threadIdx.x) >> 6;
  int lane = threadIdx.x & 63;
  int i = widx * 16 + 15;
  if (i > B - 2) return;
  const float* a = q + (size_t)i * DIM + lane * 4;
  float4 x = *reinterpret_cast<const float4*>(a);
  float4 y = *reinterpret_cast<const float4*>(a + DIM);
  float dx = y.x-x.x, dy = y.y-x.y, dz = y.z-x.z, dw = y.w-x.w;
  float sd = dx*dx + dy*dy + dz*dz + dw*dw;
  #pragma unroll
  for (int o = 1; o < 64; o <<= 1) sd += __shfl_xor(sd, o);
  if (lane == 0) out_s[i] = (sqrtf(sd) < 0.8f) ? 1.0f : 0.0f;
}

extern "C" void kernel_launch(void* const* d_in, const int* in_sizes, int n_in,
                              void* d_out, int out_size, void* d_ws, size_t ws_size,
                              hipStream_t stream) {
  const float* q  = (const float*)d_in[0];
  const float* mk = (const float*)d_in[1];
  const float* mv = (const float*)d_in[2];
  int B = in_sizes[0] / DIM;            // 131072
  float* o = (float*)d_out;
  float* w = o + (size_t)B * DIM;
  float* s = w + (size_t)B * MEMN;
  u16* knf = (u16*)d_ws;                         // 256 KB
  u16* vtf = (u16*)((char*)d_ws + 262144);       // 256 KB
  prep_keys<<<128, 256, 0, stream>>>(mk, knf);
  prep_vals<<<128, 256, 0, stream>>>(mv, vtf);
  fused_main<<<B / 32, 256, 0, stream>>>(q, knf, vtf, o, w, s);
  int nwaves = B / 16;
  scene_bound<<<(nwaves + 3) / 4, 256, 0, stream>>>(q, s, B);
}

// Round 8
// 180.112 us; speedup vs baseline: 1.0718x; 1.0718x over previous
//
#include <hip/hip_runtime.h>
#include <hip/hip_bf16.h>

#define DIM 256
#define MEMN 512
#define TEMPF 10.0f

typedef float f32x4 __attribute__((ext_vector_type(4)));
typedef __bf16 bf16x8 __attribute__((ext_vector_type(8)));
typedef unsigned int u32;
typedef unsigned short u16;

__device__ __forceinline__ u16 bf16bits(float x) {
  __bf16 h = (__bf16)x;
  return __builtin_bit_cast(u16, h);
}
__device__ __forceinline__ u32 pack2(float a, float b) {
  return (u32)bf16bits(a) | ((u32)bf16bits(b) << 16);
}

// KnFrag[kc][mt][lane][j] = Kn_norm[mt*16+(lane&15)][kc*32+(lane>>4)*8+j], kc<8, mt<32
__global__ void prep_keys(const float* __restrict__ keys, u16* __restrict__ knf) {
  int lane = threadIdx.x & 63;
  int m = blockIdx.x * 4 + (threadIdx.x >> 6);
  float4 v = *reinterpret_cast<const float4*>(keys + (size_t)m * DIM + lane * 4);
  float ss = v.x*v.x + v.y*v.y + v.z*v.z + v.w*v.w;
  #pragma unroll
  for (int o = 1; o < 64; o <<= 1) ss += __shfl_xor(ss, o);
  float rn = 1.0f / fmaxf(sqrtf(ss), 1e-12f);
  float vals[4] = {v.x*rn, v.y*rn, v.z*rn, v.w*rn};
  int mt = m >> 4, ml = m & 15;
  #pragma unroll
  for (int t = 0; t < 4; ++t) {
    int d = lane * 4 + t;
    int kc = d >> 5, gg = (d >> 3) & 3, j = d & 7;
    knf[(size_t)((kc*32 + mt)*64 + gg*16 + ml)*8 + j] = bf16bits(vals[t]);
  }
}

// VtFrag[kc][dt][lane][j] = V[kc*32+(lane>>4)*8+j][dt*16+(lane&15)], kc<16, dt<16
__global__ void prep_vals(const float* __restrict__ mv, u16* __restrict__ vtf) {
  int lane = threadIdx.x & 63;
  int m = blockIdx.x * 4 + (threadIdx.x >> 6);
  float4 v = *reinterpret_cast<const float4*>(mv + (size_t)m * DIM + lane * 4);
  float vals[4] = {v.x, v.y, v.z, v.w};
  int kc = m >> 5, gg = (m >> 3) & 3, j = m & 7;
  #pragma unroll
  for (int t = 0; t < 4; ++t) {
    int d = lane * 4 + t;
    int dt = d >> 4, dl = d & 15;
    vtf[(size_t)((kc*16 + dt)*64 + gg*16 + dl)*8 + j] = bf16bits(vals[t]);
  }
}

// 256 threads (4 waves), 64 rows/block, 2 blocks/CU.
// GEMM1: wave w owns m-quarter [128w,128w+128) x 64 rows (Q B-frags via LDS).
// GEMM2: wave w owns d-quarter [64w,64w+64)   x 64 rows (W B-frags via LDS).
// A-fragments (K,V) direct from global (L2-resident). Epilogue: O and W are
// transposed through LDS so EVERY global store is a contiguous 1KB row-span
// per wave-instruction (fill-kernel-like write streams).
__global__ __launch_bounds__(256, 2) void fused_main(
    const float* __restrict__ q, const u16* __restrict__ knf,
    const u16* __restrict__ vtf, float* __restrict__ out_o,
    float* __restrict__ out_w, float* __restrict__ out_s) {
  // [0,32768): Q-frags (gr*8+kc)*1024 + lane*16 (dead after GEMM1)
  // [0,65536): W-frags (kcw*4+gr)*1024 + lane*16 (overlays Q after barrier #2)
  //            then O / W-half f32 transpose tiles (after barrier #4)
  // [65536,66560): psb row-sum partials; [66560,66816): rnb 1/||q||
  __shared__ __align__(16) char lds[66816];
  const int tid = threadIdx.x;
  const int wave = tid >> 6, lane = tid & 63;
  const int g = lane >> 4, c = lane & 15;
  const int browbase = blockIdx.x * 64;
  const int myrow = browbase + wave * 16 + c;

  float* psb = reinterpret_cast<float*>(lds + 65536);
  float* rnb = reinterpret_cast<float*>(lds + 66560);

  // ---- prologue: own 16 rows' Q -> scene diff, sum-sq, bf16 B-frags to LDS
  const float* qrow = q + (size_t)myrow * DIM + g * 8;
  float sd = 0.f, ss = 0.f;
  #pragma unroll
  for (int kc = 0; kc < 8; ++kc) {
    float4 a = *reinterpret_cast<const float4*>(qrow + kc * 32);
    float4 b = *reinterpret_cast<const float4*>(qrow + kc * 32 + 4);
    float x[8] = {a.x, a.y, a.z, a.w, b.x, b.y, b.z, b.w};
    bf16x8 qb;
    #pragma unroll
    for (int e = 0; e < 8; ++e) {
      float nb = __shfl_down(x[e], 1);       // row c+1 (valid c<15)
      float d0 = nb - x[e];
      sd += d0 * d0;
      ss += x[e] * x[e];
      qb[e] = (__bf16)x[e];                  // deferred norm -> exp scale
    }
    *reinterpret_cast<bf16x8*>(lds + (wave*8 + kc)*1024 + lane*16) = qb;
  }
  sd += __shfl_xor(sd, 16); sd += __shfl_xor(sd, 32);
  ss += __shfl_xor(ss, 16); ss += __shfl_xor(ss, 32);
  if (g == 0 && c < 15)
    out_s[myrow] = (sqrtf(sd) < 0.8f) ? 1.0f : 0.0f;
  float rn = 1.0f / fmaxf(sqrtf(ss), 1e-12f);
  if (g == 0) rnb[wave*16 + c] = rn;
  __syncthreads();                           // #1: Q-frags + rn visible

  float scale_r[4];
  #pragma unroll
  for (int gr = 0; gr < 4; ++gr) scale_r[gr] = TEMPF * rnb[gr*16 + c];

  // ---- GEMM1: S^T[m in wave-quarter][64 rows]; A (K) direct from L2
  f32x4 acc[8][4];
  #pragma unroll
  for (int mt = 0; mt < 8; ++mt)
    #pragma unroll
    for (int gr = 0; gr < 4; ++gr) { f32x4 z = {}; acc[mt][gr] = z; }

  #pragma unroll
  for (int kc = 0; kc < 8; ++kc) {
    bf16x8 bfr[4];
    #pragma unroll
    for (int gr = 0; gr < 4; ++gr)
      bfr[gr] = *reinterpret_cast<const bf16x8*>(lds + (gr*8 + kc)*1024 + lane*16);
    bf16x8 afr[8];
    #pragma unroll
    for (int mt = 0; mt < 8; ++mt)
      afr[mt] = *reinterpret_cast<const bf16x8*>(
          knf + (size_t)(kc*32 + wave*8 + mt)*512 + lane*8);
    #pragma unroll
    for (int mt = 0; mt < 8; ++mt)
      #pragma unroll
      for (int gr = 0; gr < 4; ++gr)
        acc[mt][gr] = __builtin_amdgcn_mfma_f32_16x16x32_bf16(afr[mt], bfr[gr], acc[mt][gr], 0, 0, 0);
  }
  // acc[mt][gr][i] = S^T[m=128w+16mt+4g+i][row=gr*16+c]

  // ---- exp + partial row sums
  float psum[4] = {0.f, 0.f, 0.f, 0.f};
  #pragma unroll
  for (int mt = 0; mt < 8; ++mt)
    #pragma unroll
    for (int gr = 0; gr < 4; ++gr)
      #pragma unroll
      for (int i = 0; i < 4; ++i) {
        float e = __expf(acc[mt][gr][i] * scale_r[gr]);
        acc[mt][gr][i] = e;
        psum[gr] += e;
      }
  #pragma unroll
  for (int gr = 0; gr < 4; ++gr) {
    psum[gr] += __shfl_xor(psum[gr], 16);
    psum[gr] += __shfl_xor(psum[gr], 32);
  }
  if (g == 0) {
    #pragma unroll
    for (int gr = 0; gr < 4; ++gr)
      psb[(wave*4 + gr)*16 + c] = psum[gr];
  }
  __syncthreads();                           // #2: partials visible; Q reads done

  float rcp_r[4];
  #pragma unroll
  for (int gr = 0; gr < 4; ++gr) {
    float t = psb[(0*4 + gr)*16 + c] + psb[(1*4 + gr)*16 + c]
            + psb[(2*4 + gr)*16 + c] + psb[(3*4 + gr)*16 + c];
    rcp_r[gr] = 1.0f / t;
  }
  // fold rcp into acc: acc becomes final W values (f32)
  #pragma unroll
  for (int mt = 0; mt < 8; ++mt)
    #pragma unroll
    for (int gr = 0; gr < 4; ++gr)
      #pragma unroll
      for (int i = 0; i < 4; ++i)
        acc[mt][gr][i] *= rcp_r[gr];

  // ---- W-frags (bf16) into LDS (overlays Q region)
  // slot (kcw,gr): lane (g2,c2) j holds W[gr*16+c2][kcw*32+g2*8+j]
  // writer: kcw=4w+(mt>>1), g2=(mt&1)*2+(g>>1), j0=(g&1)*4  (round-6-verified)
  #pragma unroll
  for (int mt = 0; mt < 8; ++mt) {
    int kcw = 4*wave + (mt >> 1);
    int lane_t = ((mt & 1)*2 + (g >> 1))*16 + c;
    #pragma unroll
    for (int gr = 0; gr < 4; ++gr) {
      u32 lo = pack2(acc[mt][gr][0], acc[mt][gr][1]);
      u32 hi = pack2(acc[mt][gr][2], acc[mt][gr][3]);
      u32* dst = reinterpret_cast<u32*>(lds + (size_t)(kcw*4 + gr)*1024 + lane_t*16 + (g & 1)*8);
      dst[0] = lo; dst[1] = hi;
    }
  }
  __syncthreads();                           // #3: W-frags visible

  // ---- GEMM2: O^T[d in wave-quarter][64 rows]; A (V) direct from L2
  f32x4 oacc[4][4];
  #pragma unroll
  for (int dt = 0; dt < 4; ++dt)
    #pragma unroll
    for (int gr = 0; gr < 4; ++gr) { f32x4 z = {}; oacc[dt][gr] = z; }

  #pragma unroll
  for (int kc2 = 0; kc2 < 16; ++kc2) {
    bf16x8 bfr[4];
    #pragma unroll
    for (int gr = 0; gr < 4; ++gr)
      bfr[gr] = *reinterpret_cast<const bf16x8*>(lds + (size_t)(kc2*4 + gr)*1024 + lane*16);
    bf16x8 afr[4];
    #pragma unroll
    for (int dt = 0; dt < 4; ++dt)
      afr[dt] = *reinterpret_cast<const bf16x8*>(
          vtf + (size_t)(kc2*16 + wave*4 + dt)*512 + lane*8);
    #pragma unroll
    for (int dt = 0; dt < 4; ++dt)
      #pragma unroll
      for (int gr = 0; gr < 4; ++gr)
        oacc[dt][gr] = __builtin_amdgcn_mfma_f32_16x16x32_bf16(afr[dt], bfr[gr], oacc[dt][gr], 0, 0, 0);
  }
  __syncthreads();                           // #4: frag region dead

  // ---- epilogue O: LDS transpose (XOR swizzle byte^=(row&15)<<4) -> 1KB-row stores
  #pragma unroll
  for (int dt = 0; dt < 4; ++dt)
    #pragma unroll
    for (int gr = 0; gr < 4; ++gr) {
      int row = gr*16 + c;
      int d0 = (wave*4 + dt)*16 + 4*g;       // 4-aligned col base of the f32x4
      *reinterpret_cast<f32x4*>(lds + row*1024 + ((d0*4) ^ (c*16))) = oacc[dt][gr];
    }
  __syncthreads();                           // #5
  #pragma unroll
  for (int r = 0; r < 16; ++r) {
    int row = wave*16 + r;
    f32x4 t = *reinterpret_cast<const f32x4*>(lds + row*1024 + ((lane*16) ^ (r*16)));
    *reinterpret_cast<f32x4*>(out_o + (size_t)(browbase + row)*DIM + lane*4) = t;
  }

  // ---- epilogue W: two 64KB halves (cols [256h,256h+256)); writers = waves 2h,2h+1
  #pragma unroll
  for (int h = 0; h < 2; ++h) {
    __syncthreads();                         // region free
    if ((wave >> 1) == h) {
      int wl = wave & 1;
      #pragma unroll
      for (int mt = 0; mt < 8; ++mt)
        #pragma unroll
        for (int gr = 0; gr < 4; ++gr) {
          int row = gr*16 + c;
          int m0 = wl*128 + mt*16 + 4*g;     // col-in-half base, 4-aligned
          *reinterpret_cast<f32x4*>(lds + row*1024 + ((m0*4) ^ (c*16))) = acc[mt][gr];
        }
    }
    __syncthreads();
    #pragma unroll
    for (int r = 0; r < 16; ++r) {
      int row = wave*16 + r;
      f32x4 t = *reinterpret_cast<const f32x4*>(lds + row*1024 + ((lane*16) ^ (r*16)));
      *reinterpret_cast<f32x4*>(out_w + (size_t)(browbase + row)*MEMN + h*256 + lane*4) = t;
    }
  }
}

// Boundary scene diffs: i % 16 == 15 (one wave per i)
__global__ void scene_bound(const float* __restrict__ q, float* __restrict__ out_s, int B) {
  int widx = (blockIdx.x * blockDim.x + threadIdx.x) >> 6;
  int lane = threadIdx.x & 63;
  int i = widx * 16 + 15;
  if (i > B - 2) return;
  const float* a = q + (size_t)i * DIM + lane * 4;
  float4 x = *reinterpret_cast<const float4*>(a);
  float4 y = *reinterpret_cast<const float4*>(a + DIM);
  float dx = y.x-x.x, dy = y.y-x.y, dz = y.z-x.z, dw = y.w-x.w;
  float sd = dx*dx + dy*dy + dz*dz + dw*dw;
  #pragma unroll
  for (int o = 1; o < 64; o <<= 1) sd += __shfl_xor(sd, o);
  if (lane == 0) out_s[i] = (sqrtf(sd) < 0.8f) ? 1.0f : 0.0f;
}

extern "C" void kernel_launch(void* const* d_in, const int* in_sizes, int n_in,
                              void* d_out, int out_size, void* d_ws, size_t ws_size,
                              hipStream_t stream) {
  const float* q  = (const float*)d_in[0];
  const float* mk = (const float*)d_in[1];
  const float* mv = (const float*)d_in[2];
  int B = in_sizes[0] / DIM;            // 131072
  float* o = (float*)d_out;
  float* w = o + (size_t)B * DIM;
  float* s = w + (size_t)B * MEMN;
  u16* knf = (u16*)d_ws;                         // 256 KB
  u16* vtf = (u16*)((char*)d_ws + 262144);       // 256 KB
  prep_keys<<<128, 256, 0, stream>>>(mk, knf);
  prep_vals<<<128, 256, 0, stream>>>(mv, vtf);
  fused_main<<<B / 64, 256, 0, stream>>>(q, knf, vtf, o, w, s);
  int nwaves = B / 16;
  scene_bound<<<(nwaves + 3) / 4, 256, 0, stream>>>(q, s, B);
}